// Round 6
// baseline (220.861 us; speedup 1.0000x reference)
//
#include <hip/hip_runtime.h>
#include <cstdint>
#include <cstddef>

// CausalSelfAttention MI355X (gfx950). fp32 I/O, bf16 MFMA compute, fp32 accum.
// B=2, T=2048, C=1024, H=16, Dh=64.
// [cast f32->bf16 + device rope-table] -> [QKV gemm: 256x256 8-phase template]
// -> [flash attention: SPLIT-K (24 longest-first items/bh, 768 blocks);
// BARRIER-FREE main loop: K/V fragments loaded DIRECTLY from global (L1/L2-hot
// 16KB tiles; all 4 waves read same addresses -> L1 broadcast), LDS only for
// Q-stage + wave-private P strip; static-max softmax partials add linearly]
// -> [attn_reduce] -> [gemm proj (m97)].
// Round-6 lesson: NEVER dynamically index register arrays. All static here.

typedef short bf16x8 __attribute__((ext_vector_type(8)));
typedef float floatx4 __attribute__((ext_vector_type(4)));
typedef float floatx2 __attribute__((ext_vector_type(2)));
typedef unsigned short ushortx8 __attribute__((ext_vector_type(8)));
typedef unsigned short ushortx4 __attribute__((ext_vector_type(4)));
typedef unsigned int uintx2 __attribute__((ext_vector_type(2)));

#define DEVI __device__ __forceinline__

DEVI float bf2f(unsigned short u) {
    unsigned int x = ((unsigned int)u) << 16;
    return __builtin_bit_cast(float, x);
}
DEVI unsigned short f2bf(float f) {
    unsigned int u = __builtin_bit_cast(unsigned int, f);
    u += 0x7fffu + ((u >> 16) & 1u);   // RNE; finite values only
    return (unsigned short)(u >> 16);
}
// pack 2 fp32 -> 2 bf16 in one dword (round-half-up; inputs >= 0 here)
DEVI unsigned int pkbf2(float a, float b) {
    unsigned int ua = __builtin_bit_cast(unsigned int, a) + 0x8000u;
    unsigned int ub = __builtin_bit_cast(unsigned int, b) + 0x8000u;
    return __builtin_amdgcn_perm(ub, ua, 0x07060302);
}

// async global->LDS, 16B per lane; LDS dest = wave-uniform base + lane*16.
DEVI void glds16(const unsigned short* g, unsigned short* l) {
    __builtin_amdgcn_global_load_lds(
        (const __attribute__((address_space(1))) unsigned int*)g,
        (__attribute__((address_space(3))) unsigned int*)l, 16, 0, 0);
}

DEVI void cast8(unsigned short* dst, const float* src) {
    floatx4 a = *(const floatx4*)src;
    floatx4 b = *(const floatx4*)(src + 4);
    ushortx8 o;
    o[0] = f2bf(a[0]); o[1] = f2bf(a[1]); o[2] = f2bf(a[2]); o[3] = f2bf(a[3]);
    o[4] = f2bf(b[0]); o[5] = f2bf(b[1]); o[6] = f2bf(b[2]); o[7] = f2bf(b[3]);
    *(ushortx8*)dst = o;
}

// ---------------------------------------------------------------------------
__global__ __launch_bounds__(256)
void cast_inputs(const float* __restrict__ x, const float* __restrict__ wa,
                 const float* __restrict__ wp,
                 unsigned short* __restrict__ xb, unsigned short* __restrict__ wab,
                 unsigned short* __restrict__ wpb, float* __restrict__ ropetab)
{
    size_t g = (size_t)blockIdx.x * 256 + threadIdx.x;
    size_t stride = (size_t)gridDim.x * 256;
    for (size_t i = g; i < (4194304 / 8); i += stride) cast8(xb  + i * 8, x  + i * 8);
    for (size_t i = g; i < (3145728 / 8); i += stride) cast8(wab + i * 8, wa + i * 8);
    for (size_t i = g; i < (1048576 / 8); i += stride) cast8(wpb + i * 8, wp + i * 8);
    // rope table: [t=0..2047][f=0..31] -> (cos, sin) of t * 1e4^(-f/32).
    for (size_t i = g; i < 65536; i += stride) {
        int t = (int)(i >> 5), f = (int)(i & 31);
        float ang = (float)t * __expf(-(float)f * 0.28782313662425572f); // ln(1e4)/32
        float sn, cs;
        __sincosf(ang, &sn, &cs);
        ropetab[2 * i]     = cs;
        ropetab[2 * i + 1] = sn;
    }
}

// ---------------------------------------------------------------------------
// QKV GEMM, 8-phase 256^2 template. C[M=4096,N=3072] = A[M,1024] @ B[N,1024]^T.
// ---------------------------------------------------------------------------
__global__ __launch_bounds__(512, 2)
void gemm_qkv_8ph(const unsigned short* __restrict__ A,
                  const unsigned short* __restrict__ B,
                  const float* __restrict__ ropetab,
                  unsigned short* __restrict__ Cqk,
                  unsigned short* __restrict__ Vt)
{
    __shared__ __align__(16) unsigned short lds[2][2][256 * 64]; // [buf][A/B][..] 128KiB

    const int tid  = threadIdx.x;
    const int lane = tid & 63;
    const int w    = tid >> 6;         // 0..7
    const int wm   = w >> 2;           // 0..1 (output row half)
    const int wn   = w & 3;            // 0..3 (output col quarter = one head)
    const int quad = lane >> 4;
    const int lm   = lane & 15;

    // bijective XCD swizzle (192 blocks, 192 % 8 == 0)
    const int lin = blockIdx.y * 12 + blockIdx.x;
    const int s   = (lin & 7) * 24 + (lin >> 3);
    const int m0  = (s / 12) * 256;
    const int n0  = (s % 12) * 256;

    const int srow = tid >> 3;                                       // 0..63
    const int scol = (((tid & 7) ^ ((tid >> 3) & 7)) * 8);           // pre-swizzled
    const int ldst = w * 512;                                        // wave LDS base

#define STG_A(u, WBi, kq) glds16(&A[(size_t)(m0 + (u) * 64 + srow) * 1024 + (kq) + scol], \
                                 &lds[WBi][0][(u) * 4096 + ldst])
#define STG_B(u, WBi, kq) glds16(&B[(size_t)(n0 + (u) * 64 + srow) * 1024 + (kq) + scol], \
                                 &lds[WBi][1][(u) * 4096 + ldst])
#define RD_A(RBi, rrow, kk) (*(const bf16x8*)&lds[RBi][0][(rrow) * 64 + ((((kk) * 4 + quad) ^ ((rrow) & 7)) * 8)])
#define RD_B(RBi, rrow, kk) (*(const bf16x8*)&lds[RBi][1][(rrow) * 64 + ((((kk) * 4 + quad) ^ ((rrow) & 7)) * 8)])

    floatx4 acc[8][4] = {};
    bf16x8 afr[4][2];
    bf16x8 bfr[4][2];

#define MQ(MB, JB)                                                              \
  do {                                                                          \
    _Pragma("unroll")                                                           \
    for (int kk = 0; kk < 2; ++kk)                                              \
      _Pragma("unroll")                                                         \
      for (int mi = 0; mi < 4; ++mi)                                            \
        _Pragma("unroll")                                                       \
        for (int j2 = 0; j2 < 2; ++j2)                                          \
          acc[(MB) + mi][(JB) + j2] = __builtin_amdgcn_mfma_f32_16x16x32_bf16(  \
              afr[mi][kk], bfr[(JB) + j2][kk], acc[(MB) + mi][(JB) + j2], 0, 0, 0); \
  } while (0)

#define TILE(RBi, WBi, KT, LASTF)                                               \
  do {                                                                          \
    const int kn = ((KT) + 1) * 64;                                             \
    if (!(LASTF)) { STG_B(0, WBi, kn); STG_B(1, WBi, kn); }                     \
    _Pragma("unroll")                                                           \
    for (int kk = 0; kk < 2; ++kk) {                                            \
      _Pragma("unroll")                                                         \
      for (int mi = 0; mi < 4; ++mi)                                            \
        afr[mi][kk] = RD_A(RBi, wm * 128 + mi * 16 + lm, kk);                   \
      _Pragma("unroll")                                                         \
      for (int j2 = 0; j2 < 2; ++j2)                                            \
        bfr[j2][kk] = RD_B(RBi, wn * 64 + j2 * 16 + lm, kk);                    \
    }                                                                           \
    asm volatile("s_waitcnt lgkmcnt(8)" ::: "memory");                          \
    __builtin_amdgcn_s_barrier();                                               \
    asm volatile("s_waitcnt lgkmcnt(0)" ::: "memory");                          \
    __builtin_amdgcn_s_setprio(1); MQ(0, 0); __builtin_amdgcn_s_setprio(0);     \
    __builtin_amdgcn_s_barrier();                                               \
    if (!(LASTF)) { STG_B(2, WBi, kn); STG_B(3, WBi, kn); }                     \
    _Pragma("unroll")                                                           \
    for (int kk = 0; kk < 2; ++kk)                                              \
      _Pragma("unroll")                                                         \
      for (int j2 = 0; j2 < 2; ++j2)                                            \
        bfr[2 + j2][kk] = RD_B(RBi, wn * 64 + (2 + j2) * 16 + lm, kk);          \
    if (!(LASTF)) { asm volatile("s_waitcnt vmcnt(4)" ::: "memory"); }          \
    else          { asm volatile("s_waitcnt vmcnt(0)" ::: "memory"); }          \
    __builtin_amdgcn_s_barrier();                                               \
    asm volatile("s_waitcnt lgkmcnt(0)" ::: "memory");                          \
    __builtin_amdgcn_s_setprio(1); MQ(0, 2); __builtin_amdgcn_s_setprio(0);     \
    __builtin_amdgcn_s_barrier();                                               \
    if (!(LASTF)) { STG_A(0, WBi, kn); STG_A(2, WBi, kn); }                     \
    _Pragma("unroll")                                                           \
    for (int kk = 0; kk < 2; ++kk)                                              \
      _Pragma("unroll")                                                         \
      for (int mi = 0; mi < 4; ++mi)                                            \
        afr[mi][kk] = RD_A(RBi, wm * 128 + 64 + mi * 16 + lm, kk);              \
    __builtin_amdgcn_s_barrier();                                               \
    asm volatile("s_waitcnt lgkmcnt(0)" ::: "memory");                          \
    __builtin_amdgcn_s_setprio(1); MQ(4, 2); __builtin_amdgcn_s_setprio(0);     \
    __builtin_amdgcn_s_barrier();                                               \
    if (!(LASTF)) { STG_A(1, WBi, kn); STG_A(3, WBi, kn);                       \
                    asm volatile("s_waitcnt vmcnt(2)" ::: "memory"); }          \
    __builtin_amdgcn_s_barrier();                                               \
    __builtin_amdgcn_s_setprio(1); MQ(4, 0); __builtin_amdgcn_s_setprio(0);     \
    __builtin_amdgcn_s_barrier();                                               \
  } while (0)

    STG_B(0, 0, 0); STG_B(1, 0, 0); STG_B(2, 0, 0); STG_B(3, 0, 0);
    STG_A(0, 0, 0); STG_A(2, 0, 0); STG_A(1, 0, 0); STG_A(3, 0, 0);
    asm volatile("s_waitcnt vmcnt(2)" ::: "memory");
    __builtin_amdgcn_s_barrier();

    for (int kt = 0; kt < 14; kt += 2) {
        TILE(0, 1, kt, false);
        TILE(1, 0, kt + 1, false);
    }
    TILE(0, 1, 14, false);
    TILE(1, 0, 15, true);

    // -------- fused epilogue: RMSNorm + RoPE via precomputed table --------
    const bool is_v = (n0 + wn * 64) >= 2048;   // wave-uniform; one head per wave
    if (!is_v) {
        const floatx2* rtab = (const floatx2*)ropetab;
        #pragma unroll
        for (int mi = 0; mi < 8; ++mi) {
            float rn[4];
            #pragma unroll
            for (int r = 0; r < 4; ++r) {
                float ss = 0.0f;
                #pragma unroll
                for (int j = 0; j < 4; ++j) ss += acc[mi][j][r] * acc[mi][j][r];
                ss += __shfl_xor(ss, 1, 64);
                ss += __shfl_xor(ss, 2, 64);
                ss += __shfl_xor(ss, 4, 64);
                ss += __shfl_xor(ss, 8, 64);
                rn[r] = rsqrtf(ss * (1.0f / 64.0f) + 1.1920929e-07f);
            }
            #pragma unroll
            for (int r = 0; r < 4; ++r) {
                int row = m0 + wm * 128 + mi * 16 + quad * 4 + r;
                int t = row & 2047;
                floatx2 cs0 = rtab[t * 32 + lm];        // f = lm      (j=0,2)
                floatx2 cs1 = rtab[t * 32 + 16 + lm];   // f = 16+lm   (j=1,3)
                float g = rn[r];
                #pragma unroll
                for (int j = 0; j < 4; ++j) {
                    int d = j * 16 + lm;
                    float cs = (j & 1) ? cs1[0] : cs0[0];
                    float sn = (j & 1) ? cs1[1] : cs0[1];
                    float v  = acc[mi][j][r] * g;
                    float vp = acc[mi][j ^ 2][r] * g;          // partner d^32
                    float sgn = (d < 32) ? -1.0f : 1.0f;       // (-x2, x1)
                    Cqk[(size_t)row * 2048 + (n0 + wn * 64 + d)] =
                        f2bf(v * cs + sgn * vp * sn);
                }
            }
        }
    } else {
        #pragma unroll
        for (int mi = 0; mi < 8; ++mi)
            #pragma unroll
            for (int j = 0; j < 4; ++j) {
                int col  = n0 + wn * 64 + j * 16 + lm;
                int row0 = m0 + wm * 128 + mi * 16 + quad * 4;
                int bq = row0 >> 11, t0 = row0 & 2047;
                ushortx4 pk;
                #pragma unroll
                for (int r = 0; r < 4; ++r) pk[r] = f2bf(acc[mi][j][r]);
                *(ushortx4*)&Vt[((size_t)(bq * 1024 + (col - 2048))) * 2048 + t0] = pk;
            }
    }
#undef TILE
#undef MQ
#undef RD_A
#undef RD_B
#undef STG_A
#undef STG_B
}

// ---------------------------------------------------------------------------
// m97-structure GEMM (proj only). C[M,N] = A[M,K] @ B[N,K]^T.
// ---------------------------------------------------------------------------
template <int BN, int BK>
__global__ __launch_bounds__(256)
void gemm_bt(const unsigned short* __restrict__ A, const unsigned short* __restrict__ B,
             float* __restrict__ Cf, int M, int N, int K)
{
    constexpr int WCOLS = (BN == 128) ? 2 : 1;
    constexpr int WROWS = 4 / WCOLS;
    constexpr int MI    = 128 / (16 * WROWS);
    constexpr int LPR   = BK / 8;
    constexpr int RPI   = 64 / LPR;

    __shared__ __align__(16) unsigned short As[128 * BK];
    __shared__ __align__(16) unsigned short Bs[BN * BK];

    const int tid  = threadIdx.x;
    const int lane = tid & 63;
    const int w    = tid >> 6;
    const int wm   = w / WCOLS, wn = w % WCOLS;
    const int quad = lane >> 4;
    const int lm   = lane & 15;
    const int m0 = blockIdx.y * 128;
    const int n0 = blockIdx.x * BN;
    const int sr = lane / LPR;
    const int sc = (lane % LPR) * 8;

    floatx4 acc[MI][4] = {};

    for (int k0 = 0; k0 < K; k0 += BK) {
        __syncthreads();
        #pragma unroll
        for (int i = 0; i < 32 / RPI; ++i) {
            int r = w * 32 + i * RPI;
            glds16(&A[(size_t)(m0 + r + sr) * K + k0 + sc], &As[r * BK]);
        }
        #pragma unroll
        for (int i = 0; i < (BN / 4) / RPI; ++i) {
            int r = w * (BN / 4) + i * RPI;
            glds16(&B[(size_t)(n0 + r + sr) * K + k0 + sc], &Bs[r * BK]);
        }
        __syncthreads();

        #pragma unroll
        for (int kk = 0; kk < BK / 32; ++kk) {
            bf16x8 a[MI];
            #pragma unroll
            for (int i = 0; i < MI; ++i)
                a[i] = *(const bf16x8*)&As[(wm * (16 * MI) + i * 16 + lm) * BK + kk * 32 + quad * 8];
            #pragma unroll
            for (int j = 0; j < 4; ++j) {
                bf16x8 b = *(const bf16x8*)&Bs[(wn * 64 + j * 16 + lm) * BK + kk * 32 + quad * 8];
                #pragma unroll
                for (int i = 0; i < MI; ++i)
                    acc[i][j] = __builtin_amdgcn_mfma_f32_16x16x32_bf16(a[i], b, acc[i][j], 0, 0, 0);
            }
        }
    }

    #pragma unroll
    for (int i = 0; i < MI; ++i)
        #pragma unroll
        for (int j = 0; j < 4; ++j) {
            int col  = n0 + wn * 64 + j * 16 + lm;
            int row0 = m0 + wm * (16 * MI) + i * 16 + quad * 4;
            #pragma unroll
            for (int r = 0; r < 4; ++r)
                Cf[(size_t)(row0 + r) * N + col] = acc[i][j][r];
        }
}

// ---------------------------------------------------------------------------
// Flash attention, SPLIT-K, BARRIER-FREE main loop.
// QBLK=128, 256 threads / 4 waves, 32 q per wave (2 halves share K/V frags).
// K/V fragments load DIRECTLY from global (L1/L2-hot; no LDS staging, no
// double-buffer, no per-step barriers). LDS: Q stage (one barrier) then
// wave-private P strip (lgkm-ordered within wave only).
// Work item (blockIdx.y): (qt, t0, nt) longest-first; static-max softmax =>
// partial (o,l) add linearly; qt<8 direct y write, qt>=8 fp32 partials.
// ---------------------------------------------------------------------------
#define ENC(qt, t0, nt) ((qt) | ((t0) << 8) | ((nt) << 16))
__constant__ int g_items[24] = {
    ENC(15,16,16), ENC(15,0,16), ENC(14,0,16), ENC(13,0,16), ENC(12,0,16),
    ENC(11,0,16),  ENC(10,0,16), ENC(9,0,16),  ENC(8,0,16),  ENC(7,0,16),
    ENC(14,16,14), ENC(6,0,14),  ENC(13,16,12), ENC(5,0,12),
    ENC(12,16,10), ENC(4,0,10),  ENC(11,16,8),  ENC(3,0,8),
    ENC(10,16,6),  ENC(2,0,6),   ENC(9,16,4),   ENC(1,0,4),
    ENC(8,16,2),   ENC(0,0,2)
};

#define ATTN_EXP(SA, QROW, PROW, KT, DG)                                       \
  do {                                                                         \
    _Pragma("unroll")                                                          \
    for (int j = 0; j < 4; ++j) {                                              \
      float p0 = exp2f((SA)[j][0] * c1 - c2);                                  \
      float p1 = exp2f((SA)[j][1] * c1 - c2);                                  \
      float p2 = exp2f((SA)[j][2] * c1 - c2);                                  \
      float p3 = exp2f((SA)[j][3] * c1 - c2);                                  \
      if (DG) {                                                                \
        int kb = (KT) * 64 + j * 16 + quad * 4;                                \
        if (kb + 0 > (QROW)) p0 = 0.0f;                                        \
        if (kb + 1 > (QROW)) p1 = 0.0f;                                        \
        if (kb + 2 > (QROW)) p2 = 0.0f;                                        \
        if (kb + 3 > (QROW)) p3 = 0.0f;                                        \
      }                                                                        \
      uintx2 pk;                                                               \
      pk[0] = pkbf2(p0, p1);                                                   \
      pk[1] = pkbf2(p2, p3);                                                   \
      *(uintx2*)&QPs[(PROW) * 64 + (((2 * j + (quad >> 1)) ^ sx) * 8) + (quad & 1) * 4] = pk; \
    }                                                                          \
  } while (0)

#define ATTN_STEP_G(KT, DG)                                                    \
  do {                                                                         \
    const unsigned short* kro = kbase + (size_t)(KT) * 64 * 2048;              \
    const unsigned short* vco = vbase + (KT) * 64;                             \
    bf16x8 kfr[2][4];                                                          \
    _Pragma("unroll")                                                          \
    for (int kk = 0; kk < 2; ++kk)                                             \
      _Pragma("unroll")                                                        \
      for (int j = 0; j < 4; ++j)                                              \
        kfr[kk][j] = *(const bf16x8*)&kro[(size_t)(j * 16 + lm) * 2048 + kk * 32 + quad * 8]; \
    floatx4 sa0[4] = {}, sa1[4] = {};                                          \
    _Pragma("unroll")                                                          \
    for (int kk = 0; kk < 2; ++kk)                                             \
      _Pragma("unroll")                                                        \
      for (int j = 0; j < 4; ++j) {                                            \
        sa0[j] = __builtin_amdgcn_mfma_f32_16x16x32_bf16(kfr[kk][j], qf0[kk], sa0[j], 0, 0, 0); \
        sa1[j] = __builtin_amdgcn_mfma_f32_16x16x32_bf16(kfr[kk][j], qf1[kk], sa1[j], 0, 0, 0); \
      }                                                                        \
    bf16x8 vfr[2][4];                                                          \
    _Pragma("unroll")                                                          \
    for (int kk = 0; kk < 2; ++kk)                                             \
      _Pragma("unroll")                                                        \
      for (int j = 0; j < 4; ++j)                                              \
        vfr[kk][j] = *(const bf16x8*)&vco[(size_t)(j * 16 + lm) * 2048 + kk * 32 + quad * 8]; \
    ATTN_EXP(sa0, qrow0, w * 32 + lm,      KT, DG);                            \
    ATTN_EXP(sa1, qrow1, w * 32 + 16 + lm, KT, DG);                            \
    _Pragma("unroll")                                                          \
    for (int kk = 0; kk < 2; ++kk) {                                           \
      bf16x8 pf0 = *(const bf16x8*)&QPs[(w * 32 + lm) * 64 + (((kk * 4 + quad) ^ sx) * 8)]; \
      bf16x8 pf1 = *(const bf16x8*)&QPs[(w * 32 + 16 + lm) * 64 + (((kk * 4 + quad) ^ sx) * 8)]; \
      _Pragma("unroll")                                                        \
      for (int j = 0; j < 4; ++j) {                                            \
        o0[j] = __builtin_amdgcn_mfma_f32_16x16x32_bf16(pf0, vfr[kk][j], o0[j], 0, 0, 0); \
        o1[j] = __builtin_amdgcn_mfma_f32_16x16x32_bf16(pf1, vfr[kk][j], o1[j], 0, 0, 0); \
      }                                                                        \
      l0 = __builtin_amdgcn_mfma_f32_16x16x32_bf16(pf0, ones, l0, 0, 0, 0);    \
      l1 = __builtin_amdgcn_mfma_f32_16x16x32_bf16(pf1, ones, l1, 0, 0, 0);    \
    }                                                                          \
  } while (0)

__global__ __launch_bounds__(256, 3)
void attention(const unsigned short* __restrict__ qk,
               const unsigned short* __restrict__ Vt,
               unsigned short* __restrict__ Y,
               float* __restrict__ Po, float* __restrict__ Pl)
{
    __shared__ __align__(16) unsigned short QPs[128 * 64];  // Q stage, then P

    const int tid  = threadIdx.x;
    const int lane = tid & 63;
    const int w    = tid >> 6;           // 0..3 (32 q-rows each)
    const int quad = lane >> 4;
    const int lm   = lane & 15;
    const int sx   = lm & 7;             // Q/P fragment-read row xor

    const int bh = blockIdx.x;
    const int it = g_items[blockIdx.y];
    const int qt = it & 255;
    const int t0 = (it >> 8) & 255;      // first key-tile of this chunk
    const int nt = it >> 16;             // tiles in this chunk (even, >=2)
    const int b  = bh >> 4, h = bh & 15;
    const int q0 = qt * 128;
    const int qrow0 = q0 + w * 32 + lm;        // qh=0 lane q-row (S^T layout)
    const int qrow1 = qrow0 + 16;              // qh=1
    const bool mflag = (t0 + nt) == (2 * qt + 2);   // chunk contains diagonal
    const bool partial = qt >= 8;                    // 2-way split -> partials

    // Q staging addressing (LDS write swizzle, same as verified rounds)
    const int sr  = tid >> 3;            // 0..31
    const int sch = tid & 7;
    const int swz = ((sch ^ (sr & 7)) * 8);

    // direct-global K/V bases
    const unsigned short* kbase = qk + (size_t)b * 2048 * 2048 + 1024 + h * 64;
    const unsigned short* vbase = Vt + (size_t)bh * 64 * 2048;

    // stage Q tile (128 rows x 64 cols), swizzled
    #pragma unroll
    for (int p = 0; p < 4; ++p) {
        int row = p * 32 + sr;
        *(ushortx8*)&QPs[row * 64 + swz] =
            *(const ushortx8*)&qk[((size_t)(b * 2048 + q0 + row)) * 2048 + h * 64 + sch * 8];
    }
    __syncthreads();                     // the ONLY barrier

    bf16x8 qf0[2], qf1[2];
    #pragma unroll
    for (int kk = 0; kk < 2; ++kk) {
        qf0[kk] = *(const bf16x8*)&QPs[(w * 32 + lm) * 64 + (((kk * 4 + quad) ^ sx) * 8)];
        qf1[kk] = *(const bf16x8*)&QPs[(w * 32 + 16 + lm) * 64 + (((kk * 4 + quad) ^ sx) * 8)];
    }

    bf16x8 ones;
    #pragma unroll
    for (int i = 0; i < 8; ++i) ones[i] = (short)0x3F80;   // bf16 1.0

    floatx4 o0[4] = {}, o1[4] = {};
    floatx4 l0 = {}, l1 = {};
    const float c1 = 0.125f * 1.44269504f;   // scale * log2(e)
    const float c2 = 8.0f   * 1.44269504f;   // static max 8

    // nt steps; last two masked iff chunk contains the diagonal.
    const int nm = mflag ? nt - 2 : nt;
    int ct = 0;
    for (; ct < nm; ++ct) ATTN_STEP_G(t0 + ct, false);
    for (; ct < nt; ++ct) ATTN_STEP_G(t0 + ct, true);

    if (!partial) {
        float rinv0[4], rinv1[4];
        #pragma unroll
        for (int r = 0; r < 4; ++r) { rinv0[r] = 1.0f / l0[r]; rinv1[r] = 1.0f / l1[r]; }
        #pragma unroll
        for (int j = 0; j < 4; ++j) {
            int colg = h * 64 + j * 16 + lm;
            #pragma unroll
            for (int r = 0; r < 4; ++r) {
                int rowg0 = q0 + w * 32 + quad * 4 + r;
                Y[((size_t)(b * 2048 + rowg0)) * 1024 + colg] = f2bf(o0[j][r] * rinv0[r]);
                Y[((size_t)(b * 2048 + rowg0 + 16)) * 1024 + colg] = f2bf(o1[j][r] * rinv1[r]);
            }
        }
    } else {
        const int pidx = (bh * 8 + (qt - 8)) * 2 + (t0 ? 1 : 0);
        float* po = Po + (size_t)pidx * 8192;
        #pragma unroll
        for (int j = 0; j < 4; ++j)
            #pragma unroll
            for (int r = 0; r < 4; ++r) {
                int row0 = w * 32 + quad * 4 + r;
                po[row0 * 64 + j * 16 + lm]        = o0[j][r];
                po[(row0 + 16) * 64 + j * 16 + lm] = o1[j][r];
            }
        if (lm == 0) {
            float* pl = Pl + (size_t)pidx * 128;
            #pragma unroll
            for (int r = 0; r < 4; ++r) {
                pl[w * 32 + quad * 4 + r]      = l0[r];
                pl[w * 32 + 16 + quad * 4 + r] = l1[r];
            }
        }
    }
}

// ---------------------------------------------------------------------------
// Sum the 2 split-K partials for qt>=8 and write y (bf16).
// ---------------------------------------------------------------------------
__global__ __launch_bounds__(256)
void attn_reduce(const float* __restrict__ Po, const float* __restrict__ Pl,
                 unsigned short* __restrict__ Y)
{
    const int bh = blockIdx.x, qi = blockIdx.y;
    const int b = bh >> 4, h = bh & 15;
    const int q0 = (8 + qi) * 128;
    const int tid = threadIdx.x;
    const int row = tid >> 1;
    const int c0  = (tid & 1) * 32;
    const size_t base = ((size_t)(bh * 8 + qi)) * 2;
    const float* po0 = Po + (base + 0) * 8192 + row * 64 + c0;
    const float* po1 = Po + (base + 1) * 8192 + row * 64 + c0;
    const float rinv = 1.0f / (Pl[(base + 0) * 128 + row] + Pl[(base + 1) * 128 + row]);
    unsigned short* yp = Y + ((size_t)(b * 2048 + q0 + row)) * 1024 + h * 64 + c0;
    #pragma unroll
    for (int c = 0; c < 4; ++c) {
        floatx4 a  = *(const floatx4*)(po0 + c * 8);
        floatx4 a2 = *(const floatx4*)(po0 + c * 8 + 4);
        floatx4 e  = *(const floatx4*)(po1 + c * 8);
        floatx4 e2 = *(const floatx4*)(po1 + c * 8 + 4);
        ushortx8 o;
        o[0] = f2bf((a[0]  + e[0])  * rinv);
        o[1] = f2bf((a[1]  + e[1])  * rinv);
        o[2] = f2bf((a[2]  + e[2])  * rinv);
        o[3] = f2bf((a[3]  + e[3])  * rinv);
        o[4] = f2bf((a2[0] + e2[0]) * rinv);
        o[5] = f2bf((a2[1] + e2[1]) * rinv);
        o[6] = f2bf((a2[2] + e2[2]) * rinv);
        o[7] = f2bf((a2[3] + e2[3]) * rinv);
        *(ushortx8*)(yp + c * 8) = o;
    }
}

// ---------------------------------------------------------------------------
extern "C" void kernel_launch(void* const* d_in, const int* in_sizes, int n_in,
                              void* d_out, int out_size, void* d_ws, size_t ws_size,
                              hipStream_t stream)
{
    const float* x      = (const float*)d_in[0];   // [2,2048,1024] fp32
    const float* w_attn = (const float*)d_in[1];   // [3072,1024] fp32
    const float* w_proj = (const float*)d_in[2];   // [1024,1024] fp32
    float* out = (float*)d_out;                    // [2,2048,1024] fp32

    // ws: qk 16.8MB | Vt 8.4MB | y 8.4MB | wpb 2.1MB | Pl 256KB  (~36 MB)
    unsigned short* qkbuf = (unsigned short*)d_ws;
    unsigned short* Vtb   = qkbuf + (size_t)4096 * 2048;
    unsigned short* y     = Vtb   + (size_t)32 * 64 * 2048;
    unsigned short* wpb   = y     + (size_t)4096 * 1024;
    float* Plb            = (float*)(wpb + (size_t)1024 * 1024);
    // d_out doubles as scratch: [cast phase] xb/wab/ropetab; [attn phase] Po.
    // All dead before proj writes out.
    unsigned short* xb  = (unsigned short*)d_out;             // 8.4MB
    unsigned short* wab = xb + (size_t)4096 * 1024;           // 6.3MB
    float* ropetab = (float*)(wab + (size_t)3072 * 1024);     // 512KB
    float* Pob = (float*)d_out;                               // 16.78MB (= out size)

    dim3 blk(256);
    cast_inputs<<<dim3(1024), blk, 0, stream>>>(x, w_attn, w_proj, xb, wab, wpb, ropetab);
    gemm_qkv_8ph<<<dim3(12, 16), dim3(512), 0, stream>>>(xb, wab, ropetab, qkbuf, Vtb);
    attention<<<dim3(32, 24), blk, 0, stream>>>(qkbuf, Vtb, y, Pob, Plb);
    attn_reduce<<<dim3(32, 8), blk, 0, stream>>>(Pob, Plb, y);
    gemm_bt<64, 64>
        <<<dim3(16, 32), blk, 0, stream>>>(y, wpb, out, 4096, 1024, 1024);
}

// Round 7
// 175.930 us; speedup vs baseline: 1.2554x; 1.2554x over previous
//
#include <hip/hip_runtime.h>
#include <cstdint>
#include <cstddef>

// CausalSelfAttention MI355X (gfx950). fp32 I/O, bf16 MFMA compute, fp32 accum.
// B=2, T=2048, C=1024, H=16, Dh=64.
// [cast f32->bf16 + device rope-table] -> [QKV gemm: 256x256 8-phase template
// (XCD swizzle, 3-bit XOR LDS swizzle, counted vmcnt, setprio) with FUSED
// rmsnorm+rope(table) epilogue on q/k and transposed V] -> [flash attention:
// round-2 structure (QBLK=64, 4 waves, LD=72, double-buffered K/V, one
// barrier/step) + IN-REGISTER P: swapped-QK^T P layout == 16x16x16 A-fragment
// layout, so PV uses mfma_f32_16x16x16bf16_1k with pa packed in-register and
// V read as b64 B-fragments. NO P LDS round-trip.] -> [gemm proj (m97)].
// Round-6 lessons: never dynamically index register arrays; never replace LDS
// staging with 64-line global gathers.

typedef short bf16x8 __attribute__((ext_vector_type(8)));
typedef short bf16x4 __attribute__((ext_vector_type(4)));
typedef float floatx4 __attribute__((ext_vector_type(4)));
typedef float floatx2 __attribute__((ext_vector_type(2)));
typedef unsigned short ushortx8 __attribute__((ext_vector_type(8)));
typedef unsigned short ushortx4 __attribute__((ext_vector_type(4)));
typedef unsigned int uintx2 __attribute__((ext_vector_type(2)));

#define DEVI __device__ __forceinline__

DEVI float bf2f(unsigned short u) {
    unsigned int x = ((unsigned int)u) << 16;
    return __builtin_bit_cast(float, x);
}
DEVI unsigned short f2bf(float f) {
    unsigned int u = __builtin_bit_cast(unsigned int, f);
    u += 0x7fffu + ((u >> 16) & 1u);   // RNE; finite values only
    return (unsigned short)(u >> 16);
}
// pack 2 fp32 -> 2 bf16 in one dword: low16=bf(a), high16=bf(b) (inputs >= 0)
DEVI unsigned int pkbf2(float a, float b) {
    unsigned int ua = __builtin_bit_cast(unsigned int, a) + 0x8000u;
    unsigned int ub = __builtin_bit_cast(unsigned int, b) + 0x8000u;
    return __builtin_amdgcn_perm(ub, ua, 0x07060302);
}

// async global->LDS, 16B per lane; LDS dest = wave-uniform base + lane*16.
DEVI void glds16(const unsigned short* g, unsigned short* l) {
    __builtin_amdgcn_global_load_lds(
        (const __attribute__((address_space(1))) unsigned int*)g,
        (__attribute__((address_space(3))) unsigned int*)l, 16, 0, 0);
}

DEVI void cast8(unsigned short* dst, const float* src) {
    floatx4 a = *(const floatx4*)src;
    floatx4 b = *(const floatx4*)(src + 4);
    ushortx8 o;
    o[0] = f2bf(a[0]); o[1] = f2bf(a[1]); o[2] = f2bf(a[2]); o[3] = f2bf(a[3]);
    o[4] = f2bf(b[0]); o[5] = f2bf(b[1]); o[6] = f2bf(b[2]); o[7] = f2bf(b[3]);
    *(ushortx8*)dst = o;
}

// ---------------------------------------------------------------------------
__global__ __launch_bounds__(256)
void cast_inputs(const float* __restrict__ x, const float* __restrict__ wa,
                 const float* __restrict__ wp,
                 unsigned short* __restrict__ xb, unsigned short* __restrict__ wab,
                 unsigned short* __restrict__ wpb, float* __restrict__ ropetab)
{
    size_t g = (size_t)blockIdx.x * 256 + threadIdx.x;
    size_t stride = (size_t)gridDim.x * 256;
    for (size_t i = g; i < (4194304 / 8); i += stride) cast8(xb  + i * 8, x  + i * 8);
    for (size_t i = g; i < (3145728 / 8); i += stride) cast8(wab + i * 8, wa + i * 8);
    for (size_t i = g; i < (1048576 / 8); i += stride) cast8(wpb + i * 8, wp + i * 8);
    // rope table: [t=0..2047][f=0..31] -> (cos, sin) of t * 1e4^(-f/32).
    for (size_t i = g; i < 65536; i += stride) {
        int t = (int)(i >> 5), f = (int)(i & 31);
        float ang = (float)t * __expf(-(float)f * 0.28782313662425572f); // ln(1e4)/32
        float sn, cs;
        __sincosf(ang, &sn, &cs);
        ropetab[2 * i]     = cs;
        ropetab[2 * i + 1] = sn;
    }
}

// ---------------------------------------------------------------------------
// QKV GEMM, 8-phase 256^2 template. C[M=4096,N=3072] = A[M,1024] @ B[N,1024]^T.
// ---------------------------------------------------------------------------
__global__ __launch_bounds__(512, 2)
void gemm_qkv_8ph(const unsigned short* __restrict__ A,
                  const unsigned short* __restrict__ B,
                  const float* __restrict__ ropetab,
                  unsigned short* __restrict__ Cqk,
                  unsigned short* __restrict__ Vt)
{
    __shared__ __align__(16) unsigned short lds[2][2][256 * 64]; // [buf][A/B][..] 128KiB

    const int tid  = threadIdx.x;
    const int lane = tid & 63;
    const int w    = tid >> 6;         // 0..7
    const int wm   = w >> 2;           // 0..1 (output row half)
    const int wn   = w & 3;            // 0..3 (output col quarter = one head)
    const int quad = lane >> 4;
    const int lm   = lane & 15;

    // bijective XCD swizzle (192 blocks, 192 % 8 == 0)
    const int lin = blockIdx.y * 12 + blockIdx.x;
    const int s   = (lin & 7) * 24 + (lin >> 3);
    const int m0  = (s / 12) * 256;
    const int n0  = (s % 12) * 256;

    const int srow = tid >> 3;                                       // 0..63
    const int scol = (((tid & 7) ^ ((tid >> 3) & 7)) * 8);           // pre-swizzled
    const int ldst = w * 512;                                        // wave LDS base

#define STG_A(u, WBi, kq) glds16(&A[(size_t)(m0 + (u) * 64 + srow) * 1024 + (kq) + scol], \
                                 &lds[WBi][0][(u) * 4096 + ldst])
#define STG_B(u, WBi, kq) glds16(&B[(size_t)(n0 + (u) * 64 + srow) * 1024 + (kq) + scol], \
                                 &lds[WBi][1][(u) * 4096 + ldst])
#define RD_A(RBi, rrow, kk) (*(const bf16x8*)&lds[RBi][0][(rrow) * 64 + ((((kk) * 4 + quad) ^ ((rrow) & 7)) * 8)])
#define RD_B(RBi, rrow, kk) (*(const bf16x8*)&lds[RBi][1][(rrow) * 64 + ((((kk) * 4 + quad) ^ ((rrow) & 7)) * 8)])

    floatx4 acc[8][4] = {};
    bf16x8 afr[4][2];
    bf16x8 bfr[4][2];

#define MQ(MB, JB)                                                              \
  do {                                                                          \
    _Pragma("unroll")                                                           \
    for (int kk = 0; kk < 2; ++kk)                                              \
      _Pragma("unroll")                                                         \
      for (int mi = 0; mi < 4; ++mi)                                            \
        _Pragma("unroll")                                                       \
        for (int j2 = 0; j2 < 2; ++j2)                                          \
          acc[(MB) + mi][(JB) + j2] = __builtin_amdgcn_mfma_f32_16x16x32_bf16(  \
              afr[mi][kk], bfr[(JB) + j2][kk], acc[(MB) + mi][(JB) + j2], 0, 0, 0); \
  } while (0)

#define TILE(RBi, WBi, KT, LASTF)                                               \
  do {                                                                          \
    const int kn = ((KT) + 1) * 64;                                             \
    if (!(LASTF)) { STG_B(0, WBi, kn); STG_B(1, WBi, kn); }                     \
    _Pragma("unroll")                                                           \
    for (int kk = 0; kk < 2; ++kk) {                                            \
      _Pragma("unroll")                                                         \
      for (int mi = 0; mi < 4; ++mi)                                            \
        afr[mi][kk] = RD_A(RBi, wm * 128 + mi * 16 + lm, kk);                   \
      _Pragma("unroll")                                                         \
      for (int j2 = 0; j2 < 2; ++j2)                                            \
        bfr[j2][kk] = RD_B(RBi, wn * 64 + j2 * 16 + lm, kk);                    \
    }                                                                           \
    asm volatile("s_waitcnt lgkmcnt(8)" ::: "memory");                          \
    __builtin_amdgcn_s_barrier();                                               \
    asm volatile("s_waitcnt lgkmcnt(0)" ::: "memory");                          \
    __builtin_amdgcn_s_setprio(1); MQ(0, 0); __builtin_amdgcn_s_setprio(0);     \
    __builtin_amdgcn_s_barrier();                                               \
    if (!(LASTF)) { STG_B(2, WBi, kn); STG_B(3, WBi, kn); }                     \
    _Pragma("unroll")                                                           \
    for (int kk = 0; kk < 2; ++kk)                                              \
      _Pragma("unroll")                                                         \
      for (int j2 = 0; j2 < 2; ++j2)                                            \
        bfr[2 + j2][kk] = RD_B(RBi, wn * 64 + (2 + j2) * 16 + lm, kk);          \
    if (!(LASTF)) { asm volatile("s_waitcnt vmcnt(4)" ::: "memory"); }          \
    else          { asm volatile("s_waitcnt vmcnt(0)" ::: "memory"); }          \
    __builtin_amdgcn_s_barrier();                                               \
    asm volatile("s_waitcnt lgkmcnt(0)" ::: "memory");                          \
    __builtin_amdgcn_s_setprio(1); MQ(0, 2); __builtin_amdgcn_s_setprio(0);     \
    __builtin_amdgcn_s_barrier();                                               \
    if (!(LASTF)) { STG_A(0, WBi, kn); STG_A(2, WBi, kn); }                     \
    _Pragma("unroll")                                                           \
    for (int kk = 0; kk < 2; ++kk)                                              \
      _Pragma("unroll")                                                         \
      for (int mi = 0; mi < 4; ++mi)                                            \
        afr[mi][kk] = RD_A(RBi, wm * 128 + 64 + mi * 16 + lm, kk);              \
    __builtin_amdgcn_s_barrier();                                               \
    asm volatile("s_waitcnt lgkmcnt(0)" ::: "memory");                          \
    __builtin_amdgcn_s_setprio(1); MQ(4, 2); __builtin_amdgcn_s_setprio(0);     \
    __builtin_amdgcn_s_barrier();                                               \
    if (!(LASTF)) { STG_A(1, WBi, kn); STG_A(3, WBi, kn);                       \
                    asm volatile("s_waitcnt vmcnt(2)" ::: "memory"); }          \
    __builtin_amdgcn_s_barrier();                                               \
    __builtin_amdgcn_s_setprio(1); MQ(4, 0); __builtin_amdgcn_s_setprio(0);     \
    __builtin_amdgcn_s_barrier();                                               \
  } while (0)

    STG_B(0, 0, 0); STG_B(1, 0, 0); STG_B(2, 0, 0); STG_B(3, 0, 0);
    STG_A(0, 0, 0); STG_A(2, 0, 0); STG_A(1, 0, 0); STG_A(3, 0, 0);
    asm volatile("s_waitcnt vmcnt(2)" ::: "memory");
    __builtin_amdgcn_s_barrier();

    for (int kt = 0; kt < 14; kt += 2) {
        TILE(0, 1, kt, false);
        TILE(1, 0, kt + 1, false);
    }
    TILE(0, 1, 14, false);
    TILE(1, 0, 15, true);

    // -------- fused epilogue: RMSNorm + RoPE via precomputed table --------
    const bool is_v = (n0 + wn * 64) >= 2048;   // wave-uniform; one head per wave
    if (!is_v) {
        const floatx2* rtab = (const floatx2*)ropetab;
        #pragma unroll
        for (int mi = 0; mi < 8; ++mi) {
            float rn[4];
            #pragma unroll
            for (int r = 0; r < 4; ++r) {
                float ss = 0.0f;
                #pragma unroll
                for (int j = 0; j < 4; ++j) ss += acc[mi][j][r] * acc[mi][j][r];
                ss += __shfl_xor(ss, 1, 64);
                ss += __shfl_xor(ss, 2, 64);
                ss += __shfl_xor(ss, 4, 64);
                ss += __shfl_xor(ss, 8, 64);
                rn[r] = rsqrtf(ss * (1.0f / 64.0f) + 1.1920929e-07f);
            }
            #pragma unroll
            for (int r = 0; r < 4; ++r) {
                int row = m0 + wm * 128 + mi * 16 + quad * 4 + r;
                int t = row & 2047;
                floatx2 cs0 = rtab[t * 32 + lm];        // f = lm      (j=0,2)
                floatx2 cs1 = rtab[t * 32 + 16 + lm];   // f = 16+lm   (j=1,3)
                float g = rn[r];
                #pragma unroll
                for (int j = 0; j < 4; ++j) {
                    int d = j * 16 + lm;
                    float cs = (j & 1) ? cs1[0] : cs0[0];
                    float sn = (j & 1) ? cs1[1] : cs0[1];
                    float v  = acc[mi][j][r] * g;
                    float vp = acc[mi][j ^ 2][r] * g;          // partner d^32
                    float sgn = (d < 32) ? -1.0f : 1.0f;       // (-x2, x1)
                    Cqk[(size_t)row * 2048 + (n0 + wn * 64 + d)] =
                        f2bf(v * cs + sgn * vp * sn);
                }
            }
        }
    } else {
        #pragma unroll
        for (int mi = 0; mi < 8; ++mi)
            #pragma unroll
            for (int j = 0; j < 4; ++j) {
                int col  = n0 + wn * 64 + j * 16 + lm;
                int row0 = m0 + wm * 128 + mi * 16 + quad * 4;
                int bq = row0 >> 11, t0 = row0 & 2047;
                ushortx4 pk;
                #pragma unroll
                for (int r = 0; r < 4; ++r) pk[r] = f2bf(acc[mi][j][r]);
                *(ushortx4*)&Vt[((size_t)(bq * 1024 + (col - 2048))) * 2048 + t0] = pk;
            }
    }
#undef TILE
#undef MQ
#undef RD_A
#undef RD_B
#undef STG_A
#undef STG_B
}

// ---------------------------------------------------------------------------
// m97-structure GEMM (proj only). C[M,N] = A[M,K] @ B[N,K]^T.
// ---------------------------------------------------------------------------
template <int BN, int BK>
__global__ __launch_bounds__(256)
void gemm_bt(const unsigned short* __restrict__ A, const unsigned short* __restrict__ B,
             float* __restrict__ Cf, int M, int N, int K)
{
    constexpr int WCOLS = (BN == 128) ? 2 : 1;
    constexpr int WROWS = 4 / WCOLS;
    constexpr int MI    = 128 / (16 * WROWS);
    constexpr int LPR   = BK / 8;
    constexpr int RPI   = 64 / LPR;

    __shared__ __align__(16) unsigned short As[128 * BK];
    __shared__ __align__(16) unsigned short Bs[BN * BK];

    const int tid  = threadIdx.x;
    const int lane = tid & 63;
    const int w    = tid >> 6;
    const int wm   = w / WCOLS, wn = w % WCOLS;
    const int quad = lane >> 4;
    const int lm   = lane & 15;
    const int m0 = blockIdx.y * 128;
    const int n0 = blockIdx.x * BN;
    const int sr = lane / LPR;
    const int sc = (lane % LPR) * 8;

    floatx4 acc[MI][4] = {};

    for (int k0 = 0; k0 < K; k0 += BK) {
        __syncthreads();
        #pragma unroll
        for (int i = 0; i < 32 / RPI; ++i) {
            int r = w * 32 + i * RPI;
            glds16(&A[(size_t)(m0 + r + sr) * K + k0 + sc], &As[r * BK]);
        }
        #pragma unroll
        for (int i = 0; i < (BN / 4) / RPI; ++i) {
            int r = w * (BN / 4) + i * RPI;
            glds16(&B[(size_t)(n0 + r + sr) * K + k0 + sc], &Bs[r * BK]);
        }
        __syncthreads();

        #pragma unroll
        for (int kk = 0; kk < BK / 32; ++kk) {
            bf16x8 a[MI];
            #pragma unroll
            for (int i = 0; i < MI; ++i)
                a[i] = *(const bf16x8*)&As[(wm * (16 * MI) + i * 16 + lm) * BK + kk * 32 + quad * 8];
            #pragma unroll
            for (int j = 0; j < 4; ++j) {
                bf16x8 b = *(const bf16x8*)&Bs[(wn * 64 + j * 16 + lm) * BK + kk * 32 + quad * 8];
                #pragma unroll
                for (int i = 0; i < MI; ++i)
                    acc[i][j] = __builtin_amdgcn_mfma_f32_16x16x32_bf16(a[i], b, acc[i][j], 0, 0, 0);
            }
        }
    }

    #pragma unroll
    for (int i = 0; i < MI; ++i)
        #pragma unroll
        for (int j = 0; j < 4; ++j) {
            int col  = n0 + wn * 64 + j * 16 + lm;
            int row0 = m0 + wm * (16 * MI) + i * 16 + quad * 4;
            #pragma unroll
            for (int r = 0; r < 4; ++r)
                Cf[(size_t)(row0 + r) * N + col] = acc[i][j][r];
        }
}

// ---------------------------------------------------------------------------
// Flash attention (round-2 structure + in-register P).
// QBLK=64, 256 threads / 4 waves, 16 q per wave. Double-buffered K/V in LDS
// (LD=72), ONE __syncthreads per key-step, static buffer parity, peeled
// masked diagonal. QK^T: mfma_16x16x32(A=K, B=Q) -> lane(lm,quad) holds
// P[q=lm][key=j*16+quad*4+r], which IS the 16x16x16 A-fragment layout
// (A[m=lm][k=quad*4+e]). PV: mfma_f32_16x16x16bf16_1k(pa[j], vb[j][jd]) with
// vb = b64 B-fragments from Vs (B[k=quad*4+e][n=lm] = V[key][d]). Row-sums
// via mfma16(pa[j], ones4). NO P LDS traffic; no extra lgkm waits.
// ---------------------------------------------------------------------------
#define ATTN_STEP(KSc, VSc, KSn, VSn, KT, DG, LAST)                            \
  do {                                                                         \
    if (!(LAST)) {                                                             \
      *(ushortx8*)&(KSn)[r0 * LD + pc] = kreg0;                                \
      *(ushortx8*)&(KSn)[r1 * LD + pc] = kreg1;                                \
      *(ushortx8*)&(VSn)[r0 * LD + pc] = vreg0;                                \
      *(ushortx8*)&(VSn)[r1 * LD + pc] = vreg1;                                \
      if ((KT) + 2 <= qt) {                                                    \
        kreg0 = *(const ushortx8*)kp0; kreg1 = *(const ushortx8*)kp1;          \
        vreg0 = *(const ushortx8*)vp0; vreg1 = *(const ushortx8*)vp1;          \
        kp0 += (size_t)64 * 2048; kp1 += (size_t)64 * 2048;                    \
        vp0 += 64; vp1 += 64;                                                  \
      }                                                                        \
    }                                                                          \
    /* V B-fragments (independent of P: issue early, latency hides under QK) */\
    bf16x4 vb0[4], vb1[4], vb2[4], vb3[4];                                     \
    _Pragma("unroll")                                                          \
    for (int jd = 0; jd < 4; ++jd) {                                           \
      vb0[jd] = *(const bf16x4*)&(VSc)[(jd * 16 + lm) * LD +  0 + quad * 4];   \
      vb1[jd] = *(const bf16x4*)&(VSc)[(jd * 16 + lm) * LD + 16 + quad * 4];   \
      vb2[jd] = *(const bf16x4*)&(VSc)[(jd * 16 + lm) * LD + 32 + quad * 4];   \
      vb3[jd] = *(const bf16x4*)&(VSc)[(jd * 16 + lm) * LD + 48 + quad * 4];   \
    }                                                                          \
    floatx4 sa[4] = {};                                                        \
    _Pragma("unroll")                                                          \
    for (int kk = 0; kk < 2; ++kk)                                             \
      _Pragma("unroll")                                                        \
      for (int j = 0; j < 4; ++j) {                                            \
        bf16x8 kf = *(const bf16x8*)&(KSc)[(j * 16 + lm) * LD + kk * 32 + quad * 8]; \
        sa[j] = __builtin_amdgcn_mfma_f32_16x16x32_bf16(kf, qf[kk], sa[j], 0, 0, 0); \
      }                                                                        \
    bf16x4 pa[4];                                                              \
    _Pragma("unroll")                                                          \
    for (int j = 0; j < 4; ++j) {                                              \
      float p0 = exp2f(sa[j][0] * c1 - c2);                                    \
      float p1 = exp2f(sa[j][1] * c1 - c2);                                    \
      float p2 = exp2f(sa[j][2] * c1 - c2);                                    \
      float p3 = exp2f(sa[j][3] * c1 - c2);                                    \
      if (DG) {                                                                \
        int kb = (KT) * 64 + j * 16 + quad * 4;                                \
        if (kb + 0 > qrow) p0 = 0.0f;                                          \
        if (kb + 1 > qrow) p1 = 0.0f;                                          \
        if (kb + 2 > qrow) p2 = 0.0f;                                          \
        if (kb + 3 > qrow) p3 = 0.0f;                                          \
      }                                                                        \
      uintx2 pk;                                                               \
      pk[0] = pkbf2(p0, p1);                                                   \
      pk[1] = pkbf2(p2, p3);                                                   \
      pa[j] = __builtin_bit_cast(bf16x4, pk);                                  \
    }                                                                          \
    _Pragma("unroll")                                                          \
    for (int j = 0; j < 4; ++j)                                                \
      l_acc = __builtin_amdgcn_mfma_f32_16x16x16bf16_1k(pa[j], ones4, l_acc, 0, 0, 0); \
    _Pragma("unroll")                                                          \
    for (int jd = 0; jd < 4; ++jd) {                                           \
      o[jd] = __builtin_amdgcn_mfma_f32_16x16x16bf16_1k(pa[0], vb0[jd], o[jd], 0, 0, 0); \
      o[jd] = __builtin_amdgcn_mfma_f32_16x16x16bf16_1k(pa[1], vb1[jd], o[jd], 0, 0, 0); \
      o[jd] = __builtin_amdgcn_mfma_f32_16x16x16bf16_1k(pa[2], vb2[jd], o[jd], 0, 0, 0); \
      o[jd] = __builtin_amdgcn_mfma_f32_16x16x16bf16_1k(pa[3], vb3[jd], o[jd], 0, 0, 0); \
    }                                                                          \
    if (!(LAST)) __syncthreads();                                              \
  } while (0)

__global__ __launch_bounds__(256)
void attention(const unsigned short* __restrict__ qk,
               const unsigned short* __restrict__ Vt,
               unsigned short* __restrict__ Y)
{
    constexpr int LD = 72;
    __shared__ __align__(16) unsigned short QPs[64 * LD];  // Q stage only
    __shared__ __align__(16) unsigned short Ks0[64 * LD];
    __shared__ __align__(16) unsigned short Ks1[64 * LD];
    __shared__ __align__(16) unsigned short Vs0[64 * LD];
    __shared__ __align__(16) unsigned short Vs1[64 * LD];

    const int tid  = threadIdx.x;
    const int lane = tid & 63;
    const int w    = tid >> 6;
    const int quad = lane >> 4;
    const int lm   = lane & 15;

    const int bh = blockIdx.x;
    const int qt = 31 - blockIdx.y;      // longest first
    const int b  = bh >> 4, h = bh & 15;
    const int q0 = qt * 64;
    const int qrow = q0 + w * 16 + lm;   // this lane's q-row (S^T layout)

    const int r0 = tid >> 3, r1 = r0 + 32, pc = (tid & 7) * 8;
    const unsigned short* kp0 = qk + (size_t)b * 2048 * 2048 + 1024 + h * 64
                              + (size_t)r0 * 2048 + pc;
    const unsigned short* kp1 = kp0 + (size_t)32 * 2048;
    const unsigned short* vp0 = Vt + (size_t)bh * 64 * 2048 + (size_t)r0 * 2048 + pc;
    const unsigned short* vp1 = vp0 + (size_t)32 * 2048;

    // stage Q tile
    #pragma unroll
    for (int i = 0; i < 2; ++i) {
        int c = i * 256 + tid, row = c >> 3, col = (c & 7) * 8;
        *(ushortx8*)&QPs[row * LD + col] =
            *(const ushortx8*)&qk[((size_t)(b * 2048 + q0 + row)) * 2048 + h * 64 + col];
    }

    // tile 0 -> buf0 directly; prefetch tile 1 into regs
    ushortx8 kreg0 = *(const ushortx8*)kp0, kreg1 = *(const ushortx8*)kp1;
    ushortx8 vreg0 = *(const ushortx8*)vp0, vreg1 = *(const ushortx8*)vp1;
    kp0 += (size_t)64 * 2048; kp1 += (size_t)64 * 2048;
    vp0 += 64; vp1 += 64;
    *(ushortx8*)&Ks0[r0 * LD + pc] = kreg0;
    *(ushortx8*)&Ks0[r1 * LD + pc] = kreg1;
    *(ushortx8*)&Vs0[r0 * LD + pc] = vreg0;
    *(ushortx8*)&Vs0[r1 * LD + pc] = vreg1;
    if (qt >= 1) {
        kreg0 = *(const ushortx8*)kp0; kreg1 = *(const ushortx8*)kp1;
        vreg0 = *(const ushortx8*)vp0; vreg1 = *(const ushortx8*)vp1;
        kp0 += (size_t)64 * 2048; kp1 += (size_t)64 * 2048;
        vp0 += 64; vp1 += 64;
    }
    __syncthreads();                     // Q + tile0 visible

    bf16x8 qf[2];
    #pragma unroll
    for (int kk = 0; kk < 2; ++kk)
        qf[kk] = *(const bf16x8*)&QPs[(w * 16 + lm) * LD + kk * 32 + quad * 8];

    bf16x4 ones4;
    #pragma unroll
    for (int i = 0; i < 4; ++i) ones4[i] = (short)0x3F80;   // bf16 1.0

    floatx4 o[4] = {};
    floatx4 l_acc = {};                  // row-sums, same D-layout rows as o
    const float c1 = 0.125f * 1.44269504f;   // scale * log2(e)
    const float c2 = 8.0f   * 1.44269504f;   // static max 8

    // mask-free steps in pairs (buffer parity static: even kt -> buf0)
    int kt = 0;
    for (; kt + 1 < qt; kt += 2) {
        ATTN_STEP(Ks0, Vs0, Ks1, Vs1, kt,     false, false);
        ATTN_STEP(Ks1, Vs1, Ks0, Vs0, kt + 1, false, false);
    }
    if (kt < qt) {                       // kt even here; one more mask-free step
        ATTN_STEP(Ks0, Vs0, Ks1, Vs1, kt, false, false);
        // diagonal lives in buf1 (qt odd)
        ATTN_STEP(Ks1, Vs1, Ks0, Vs0, qt, true, true);
    } else {                             // kt == qt (qt even): diagonal in buf0
        ATTN_STEP(Ks0, Vs0, Ks1, Vs1, qt, true, true);
    }

    float rinv[4];
    #pragma unroll
    for (int r = 0; r < 4; ++r) rinv[r] = 1.0f / l_acc[r];

    #pragma unroll
    for (int jd = 0; jd < 4; ++jd) {
        int colg = h * 64 + jd * 16 + lm;
        #pragma unroll
        for (int r = 0; r < 4; ++r) {
            int rowg = q0 + w * 16 + quad * 4 + r;
            Y[((size_t)(b * 2048 + rowg)) * 1024 + colg] = f2bf(o[jd][r] * rinv[r]);
        }
    }
}

// ---------------------------------------------------------------------------
extern "C" void kernel_launch(void* const* d_in, const int* in_sizes, int n_in,
                              void* d_out, int out_size, void* d_ws, size_t ws_size,
                              hipStream_t stream)
{
    const float* x      = (const float*)d_in[0];   // [2,2048,1024] fp32
    const float* w_attn = (const float*)d_in[1];   // [3072,1024] fp32
    const float* w_proj = (const float*)d_in[2];   // [1024,1024] fp32
    float* out = (float*)d_out;                    // [2,2048,1024] fp32

    // ws: qk 16.8MB | Vt 8.4MB | y 8.4MB | wpb 2.1MB  (35.7 MB total)
    unsigned short* qkbuf = (unsigned short*)d_ws;
    unsigned short* Vtb   = qkbuf + (size_t)4096 * 2048;
    unsigned short* y     = Vtb   + (size_t)32 * 64 * 2048;
    unsigned short* wpb   = y     + (size_t)4096 * 1024;
    // d_out doubles as pre-cast scratch (dead before proj writes):
    unsigned short* xb  = (unsigned short*)d_out;             // 8.4MB
    unsigned short* wab = xb + (size_t)4096 * 1024;           // 6.3MB
    float* ropetab = (float*)(wab + (size_t)3072 * 1024);     // 512KB

    dim3 blk(256);
    cast_inputs<<<dim3(1024), blk, 0, stream>>>(x, w_attn, w_proj, xb, wab, wpb, ropetab);
    gemm_qkv_8ph<<<dim3(12, 16), dim3(512), 0, stream>>>(xb, wab, ropetab, qkbuf, Vtb);
    attention<<<dim3(32, 32), blk, 0, stream>>>(qkbuf, Vtb, y);
    gemm_bt<64, 64>
        <<<dim3(16, 32), blk, 0, stream>>>(y, wpb, out, 4096, 1024, 1024);
}